// Round 6
// baseline (529.831 us; speedup 1.0000x reference)
//
#include <hip/hip_runtime.h>
#include <math.h>

#define BLOCK 256
#define MS 16   // samples per block

// ---------------------------------------------------------------------------
// Kernel A: MLP
//   x(68) -> 256 -> 512 -> 256(feat) -> {128 -> 20 (cp head), 128 -> 6 (knot head)}
// Writes deta_cp -> dout[B*3 .. B*23), deta_knots_6 -> dout[B*23 .. B*29).
// One block = 16 samples; activations ping-pong in LDS [N][MS]; wave-uniform
// float4 broadcast reads; weights stream from L2. 48 KB LDS -> 3 blocks/CU.
//
// Kernel B: geometry, one THREAD per sample, serial float64, mirrors the
// reference line-for-line (Cox-de Boor with den>0 guards, atan2(dx,dy),
// first-occurrence argmax/argmin, masked range max/min). Reads deta from
// dout (written by A on the same stream). Writes cobb -> dout[0 .. B*3).
// ---------------------------------------------------------------------------

__device__ __forceinline__ void unpack16(const float* __restrict__ row, float* av){
  const float4* r4 = (const float4*)row;
  float4 a0=r4[0], a1=r4[1], a2=r4[2], a3=r4[3];
  av[0]=a0.x;  av[1]=a0.y;  av[2]=a0.z;  av[3]=a0.w;
  av[4]=a1.x;  av[5]=a1.y;  av[6]=a1.z;  av[7]=a1.w;
  av[8]=a2.x;  av[9]=a2.y;  av[10]=a2.z; av[11]=a2.w;
  av[12]=a3.x; av[13]=a3.y; av[14]=a3.z; av[15]=a3.w;
}

template<int K, int N, int VEC, bool RELU>
__device__ __forceinline__ void dense_layer(const float* __restrict__ W,
                                            const float* __restrict__ Bv,
                                            const float* sA, float* sC, int tid)
{
  static_assert(N == BLOCK*VEC, "each thread owns VEC consecutive columns");
  const int j0 = tid*VEC;
  float acc[VEC][MS];
  #pragma unroll
  for (int c=0;c<VEC;c++){
    float b = Bv[j0+c];
    #pragma unroll
    for (int m=0;m<MS;m++) acc[c][m] = b;
  }
  #pragma unroll 4
  for (int k=0;k<K;k++){
    float av[MS];
    unpack16(sA + k*MS, av);
    float w[VEC];
    if constexpr (VEC == 2){
      float2 wv = *(const float2*)(W + (size_t)k*N + j0);
      w[0]=wv.x; w[1]=wv.y;
    } else {
      w[0] = W[(size_t)k*N + j0];
    }
    #pragma unroll
    for (int c=0;c<VEC;c++){
      #pragma unroll
      for (int m=0;m<MS;m++) acc[c][m] = fmaf(av[m], w[c], acc[c][m]);
    }
  }
  #pragma unroll
  for (int c=0;c<VEC;c++){
    #pragma unroll
    for (int m=0;m<MS;m++){
      float v = acc[c][m];
      if (RELU) v = fmaxf(v, 0.f);
      sC[(size_t)(j0+c)*MS + m] = v;
    }
  }
}

extern "C" __global__ __launch_bounds__(BLOCK, 3)
void kbs_mlp(const float* __restrict__ kp,
             const float* __restrict__ w1, const float* __restrict__ b1,
             const float* __restrict__ w2, const float* __restrict__ b2,
             const float* __restrict__ w3, const float* __restrict__ b3,
             const float* __restrict__ wc1, const float* __restrict__ bc1,
             const float* __restrict__ wc2, const float* __restrict__ bc2,
             const float* __restrict__ wk1, const float* __restrict__ bk1,
             const float* __restrict__ wk2, const float* __restrict__ bk2,
             float* __restrict__ dout, int B)
{
  __shared__ float sA[512*MS];   // 32 KB
  __shared__ float sB[256*MS];   // 16 KB

  const int tid = threadIdx.x;
  const long base = (long)blockIdx.x * MS;

  // ---- stage X = keypoints.reshape(B,68) into sA as [68][MS] ----
  for (int idx = tid; idx < 68*MS; idx += BLOCK){
    int m = idx / 68, k = idx % 68;
    float v = 0.f;
    if (base + m < B) v = kp[(base + m)*68 + k];
    sA[k*MS + m] = v;
  }
  __syncthreads();

  // ---- MLP trunk (ping-pong sA <-> sB) ----
  dense_layer<68, 256, 1, true>(w1, b1, sA, sB, tid);
  __syncthreads();
  dense_layer<256,512, 2, true>(w2, b2, sB, sA, tid);
  __syncthreads();
  dense_layer<512,256, 1, true>(w3, b3, sA, sB, tid);   // feat -> sB
  __syncthreads();

  // ---- heads, stage 1 (both 256->128, half-block each) ----
  float* sHC = sA;            // [128][MS]
  float* sHK = sA + 128*MS;   // [128][MS]
  {
    const bool isC = (tid < 128);          // wave-uniform split (wave=64)
    const int j = tid & 127;
    const float* W  = isC ? wc1 : wk1;
    const float* Bv = isC ? bc1 : bk1;
    float acc[MS];
    float b = Bv[j];
    #pragma unroll
    for (int m=0;m<MS;m++) acc[m] = b;
    #pragma unroll 4
    for (int k=0;k<256;k++){
      float av[MS];
      unpack16(sB + k*MS, av);
      float w = W[k*128 + j];
      #pragma unroll
      for (int m=0;m<MS;m++) acc[m] = fmaf(av[m], w, acc[m]);
    }
    float* dst = isC ? sHC : sHK;
    #pragma unroll
    for (int m=0;m<MS;m++) dst[j*MS + m] = fmaxf(acc[m], 0.f);
  }
  __syncthreads();

  // ---- heads, stage 2 (128->20 and 128->6) ----
  float* sCPF = sB;            // [20][MS]  (deta_cp, raw)
  float* sK6  = sB + 20*MS;    // [6][MS]   (deta_knots_6, clipped)
  if (tid < 20){
    float acc[MS];
    float b = bc2[tid];
    #pragma unroll
    for (int m=0;m<MS;m++) acc[m] = b;
    for (int k=0;k<128;k++){
      float av[MS];
      unpack16(sHC + k*MS, av);
      float w = wc2[k*20 + tid];
      #pragma unroll
      for (int m=0;m<MS;m++) acc[m] = fmaf(av[m], w, acc[m]);
    }
    #pragma unroll
    for (int m=0;m<MS;m++) sCPF[tid*MS + m] = acc[m];
  } else if (tid >= 64 && tid < 70){
    const int j = tid - 64;
    float acc[MS];
    float b = bk2[j];
    #pragma unroll
    for (int m=0;m<MS;m++) acc[m] = b;
    for (int k=0;k<128;k++){
      float av[MS];
      unpack16(sHK + k*MS, av);
      float w = wk2[k*6 + j];
      #pragma unroll
      for (int m=0;m<MS;m++) acc[m] = fmaf(av[m], w, acc[m]);
    }
    #pragma unroll
    for (int m=0;m<MS;m++) sK6[j*MS + m] = fminf(fmaxf(acc[m], 0.f), 1.f);
  }
  __syncthreads();

  // ---- write deta_cp and deta_knots_6 outputs ----
  float* out_dcp = dout + (long)B*3;
  float* out_dk  = dout + (long)B*23;
  for (int idx = tid; idx < MS*20; idx += BLOCK){
    int s = idx / 20, c = idx % 20;
    if (base + s < B) out_dcp[(base+s)*20 + c] = sCPF[c*MS + s];
  }
  for (int idx = tid; idx < MS*6; idx += BLOCK){
    int s = idx / 6, c = idx % 6;
    if (base + s < B) out_dk[(base+s)*6 + c] = sK6[c*MS + s];
  }
}

// ---------------------------------------------------------------------------
// Kernel B: per-sample serial float64 geometry (reference-shaped).
// ---------------------------------------------------------------------------
extern "C" __global__ __launch_bounds__(256)
void kbs_geom(const float* __restrict__ knots_g, const float* __restrict__ cp_g,
              float* __restrict__ dout, int B)
{
  const int s = blockIdx.x * blockDim.x + threadIdx.x;
  if (s >= B) return;

  const float* dcp = dout + (long)B*3  + (long)s*20;  // deta_cp (written by A)
  const float* dk6 = dout + (long)B*23 + (long)s*6;   // deta_knots_6

  double u[14];
  #pragma unroll
  for (int i=0;i<14;i++){
    double d = (i>=4 && i<10) ? (double)dk6[i-4] : 0.0;
    u[i] = (double)knots_g[(long)s*14 + i] + d;
  }
  double cx[10], cy[10];
  #pragma unroll
  for (int i=0;i<10;i++){
    cx[i] = (double)cp_g[(long)s*20 + 2*i    ] + (double)dcp[2*i    ];
    cy[i] = (double)cp_g[(long)s*20 + 2*i + 1] + (double)dcp[2*i + 1];
  }

  double ang[33];
  double ppx = 0.0, ppy = 0.0;
  const double uend = u[13] - 1e-6;
  for (int q = 0; q < 34; ++q){
    double uq = (double)q * (1.0/33.0);
    if (uq > uend) uq = uend;
    // degree-0 basis
    double Nb[13];
    #pragma unroll
    for (int i=0;i<13;i++)
      Nb[i] = (uq >= u[i] && uq < u[i+1]) ? 1.0 : 0.0;
    // Cox-de Boor, in-place ascending (uses old Nb[i+1])
    #pragma unroll
    for (int p=1;p<=3;p++){
      #pragma unroll
      for (int i=0;i+p<13;i++){
        double ld = u[i+p]   - u[i];
        double rd = u[i+p+1] - u[i+1];
        double lf = (ld > 0.0) ? (uq - u[i])     / ld : 0.0;
        double rf = (rd > 0.0) ? (u[i+p+1] - uq) / rd : 0.0;
        Nb[i] = lf*Nb[i] + rf*Nb[i+1];
      }
    }
    double px = 0.0, py = 0.0;
    #pragma unroll
    for (int i=0;i<10;i++){ px += Nb[i]*cx[i]; py += Nb[i]*cy[i]; }
    if (q > 0)
      ang[q-1] = 57.29577951308232087679815 * atan2(px - ppx, py - ppy);
    ppx = px; ppy = py;
  }

  // first-occurrence argmax / argmin (serial, matches np.argmax/argmin)
  int imax = 0, imin = 0;
  for (int i=1;i<33;i++){
    if (ang[i] > ang[imax]) imax = i;
    if (ang[i] < ang[imin]) imin = i;
  }
  double mt = ang[imax] - ang[imin];
  int lo = imax < imin ? imax : imin;
  int hi = imax > imin ? imax : imin;

  double uM = -1e300, um = 1e300;
  for (int i=0;i<=lo;i++){ uM = fmax(uM, ang[i]); um = fmin(um, ang[i]); }
  double dM = -1e300, dm = 1e300;
  for (int i=hi;i<33;i++){ dM = fmax(dM, ang[i]); dm = fmin(dm, ang[i]); }

  dout[(long)s*3 + 0] = (float)(uM - um);  // pt
  dout[(long)s*3 + 1] = (float)mt;         // mt
  dout[(long)s*3 + 2] = (float)(dM - dm);  // tl
}

extern "C" void kernel_launch(void* const* d_in, const int* in_sizes, int n_in,
                              void* d_out, int out_size, void* d_ws, size_t ws_size,
                              hipStream_t stream)
{
  const float* kp    = (const float*)d_in[0];
  const float* knots = (const float*)d_in[1];
  const float* cp    = (const float*)d_in[2];
  const float* w1  = (const float*)d_in[3];  const float* b1  = (const float*)d_in[4];
  const float* w2  = (const float*)d_in[5];  const float* b2  = (const float*)d_in[6];
  const float* w3  = (const float*)d_in[7];  const float* b3  = (const float*)d_in[8];
  const float* wc1 = (const float*)d_in[9];  const float* bc1 = (const float*)d_in[10];
  const float* wc2 = (const float*)d_in[11]; const float* bc2 = (const float*)d_in[12];
  const float* wk1 = (const float*)d_in[13]; const float* bk1 = (const float*)d_in[14];
  const float* wk2 = (const float*)d_in[15]; const float* bk2 = (const float*)d_in[16];

  const int B = in_sizes[0] / 68;           // keypoints (B,34,2)
  const int nblkA = (B + MS - 1) / MS;
  const int nblkB = (B + 255) / 256;

  hipLaunchKernelGGL(kbs_mlp, dim3(nblkA), dim3(BLOCK), 0, stream,
                     kp, w1, b1, w2, b2, w3, b3,
                     wc1, bc1, wc2, bc2, wk1, bk1, wk2, bk2,
                     (float*)d_out, B);
  hipLaunchKernelGGL(kbs_geom, dim3(nblkB), dim3(256), 0, stream,
                     knots, cp, (float*)d_out, B);
}

// Round 8
// 520.710 us; speedup vs baseline: 1.0175x; 1.0175x over previous
//
#include <hip/hip_runtime.h>
#include <math.h>

#define BLOCK 256
#define MS 16   // samples per block

// ---------------------------------------------------------------------------
// Kernel A (MLP): one block = 16 samples. Thread tid -> (j = tid&127 column
// group, h = tid>>7 sample half). Each thread computes CPT=N/128 adjacent
// columns for 8 samples: per k-iter = 2 ds_read_b128 (broadcast) + 1 vector
// weight load + 16/32 FMAs (8:1 / 16:1 FMA:LDS ratio). Activations ping-pong
// in LDS [N][16]; 48 KB -> 3 blocks/CU.
// Kernel B (geometry): 1 thread/sample, f64, fully unrolled, register-only
// (no dynamic indexing -> no scratch).
// ---------------------------------------------------------------------------

template<int K, int CPT, bool RELU>
__device__ __forceinline__ void dense_cols(const float* __restrict__ Wcol, int ld,
                                           const float* __restrict__ Bcol,
                                           const float* sArow,   // &sA[h*8]
                                           float* sCcol)         // &sC[c0*16 + h*8]
{
  float acc[CPT][8];
  #pragma unroll
  for (int c=0;c<CPT;c++){
    float b = Bcol[c];
    #pragma unroll
    for (int m=0;m<8;m++) acc[c][m] = b;
  }
  #pragma unroll 4
  for (int k=0;k<K;k++){
    float4 a0 = *(const float4*)(sArow + k*MS);
    float4 a1 = *(const float4*)(sArow + k*MS + 4);
    float av[8] = {a0.x,a0.y,a0.z,a0.w,a1.x,a1.y,a1.z,a1.w};
    float w[CPT];
    if constexpr (CPT == 4){
      float4 wv = *(const float4*)(Wcol + (size_t)k*ld);
      w[0]=wv.x; w[1]=wv.y; w[2]=wv.z; w[3]=wv.w;
    } else {
      float2 wv = *(const float2*)(Wcol + (size_t)k*ld);
      w[0]=wv.x; w[1]=wv.y;
    }
    #pragma unroll
    for (int c=0;c<CPT;c++)
      #pragma unroll
      for (int m=0;m<8;m++) acc[c][m] = fmaf(av[m], w[c], acc[c][m]);
  }
  #pragma unroll
  for (int c=0;c<CPT;c++)
    #pragma unroll
    for (int m=0;m<8;m++){
      float v = acc[c][m];
      if (RELU) v = fmaxf(v, 0.f);
      sCcol[c*MS + m] = v;
    }
}

extern "C" __global__ __launch_bounds__(BLOCK, 3)
void kbs_mlp(const float* __restrict__ kp,
             const float* __restrict__ w1, const float* __restrict__ b1,
             const float* __restrict__ w2, const float* __restrict__ b2,
             const float* __restrict__ w3, const float* __restrict__ b3,
             const float* __restrict__ wc1, const float* __restrict__ bc1,
             const float* __restrict__ wc2, const float* __restrict__ bc2,
             const float* __restrict__ wk1, const float* __restrict__ bk1,
             const float* __restrict__ wk2, const float* __restrict__ bk2,
             float* __restrict__ dout, int B)
{
  __shared__ float sA[512*MS];   // 32 KB
  __shared__ float sB[256*MS];   // 16 KB

  const int tid = threadIdx.x;
  const int j   = tid & 127;     // column-group index
  const int h   = tid >> 7;      // sample half (0/1)
  const long base = (long)blockIdx.x * MS;

  // ---- stage X = keypoints.reshape(B,68) into sA as [68][MS] ----
  for (int idx = tid; idx < 68*MS; idx += BLOCK){
    int m = idx / 68, k = idx % 68;
    float v = 0.f;
    if (base + m < B) v = kp[(base + m)*68 + k];
    sA[k*MS + m] = v;
  }
  __syncthreads();

  // ---- L1: 68 -> 256 ----
  dense_cols<68, 2, true>(w1 + 2*j, 256, b1 + 2*j, sA + h*8, sB + (2*j)*MS + h*8);
  __syncthreads();
  // ---- L2: 256 -> 512 ----
  dense_cols<256, 4, true>(w2 + 4*j, 512, b2 + 4*j, sB + h*8, sA + (4*j)*MS + h*8);
  __syncthreads();
  // ---- L3: 512 -> 256 (feat -> sB) ----
  dense_cols<512, 2, true>(w3 + 2*j, 256, b3 + 2*j, sA + h*8, sB + (2*j)*MS + h*8);
  __syncthreads();
  // ---- heads stage 1: feat(256) -> [HC(128) | HK(128)] concat in sA ----
  {
    const int c0 = 2*j;                       // concat col (wave-uniform branch)
    const float* Wp = (c0 < 128) ? (wc1 + c0) : (wk1 + (c0 - 128));
    const float* Bp = (c0 < 128) ? (bc1 + c0) : (bk1 + (c0 - 128));
    dense_cols<256, 2, true>(Wp, 128, Bp, sB + h*8, sA + c0*MS + h*8);
  }
  __syncthreads();

  // ---- heads stage 2 (128->20 and 128->6), per-thread column, all 16 samples ----
  float* sCPF = sB;            // [20][MS]  (deta_cp, raw)
  float* sK6  = sB + 20*MS;    // [6][MS]   (deta_knots_6, clipped)
  if (tid < 20){
    float acc[MS];
    float b = bc2[tid];
    #pragma unroll
    for (int m=0;m<MS;m++) acc[m] = b;
    for (int k=0;k<128;k++){
      const float4* r4 = (const float4*)(sA + k*MS);   // HC row k
      float4 q0=r4[0], q1=r4[1], q2=r4[2], q3=r4[3];
      float av[MS] = {q0.x,q0.y,q0.z,q0.w,q1.x,q1.y,q1.z,q1.w,
                      q2.x,q2.y,q2.z,q2.w,q3.x,q3.y,q3.z,q3.w};
      float w = wc2[k*20 + tid];
      #pragma unroll
      for (int m=0;m<MS;m++) acc[m] = fmaf(av[m], w, acc[m]);
    }
    #pragma unroll
    for (int m=0;m<MS;m++) sCPF[tid*MS + m] = acc[m];
  } else if (tid >= 64 && tid < 70){
    const int jj = tid - 64;
    float acc[MS];
    float b = bk2[jj];
    #pragma unroll
    for (int m=0;m<MS;m++) acc[m] = b;
    for (int k=0;k<128;k++){
      const float4* r4 = (const float4*)(sA + (128+k)*MS);  // HK row k
      float4 q0=r4[0], q1=r4[1], q2=r4[2], q3=r4[3];
      float av[MS] = {q0.x,q0.y,q0.z,q0.w,q1.x,q1.y,q1.z,q1.w,
                      q2.x,q2.y,q2.z,q2.w,q3.x,q3.y,q3.z,q3.w};
      float w = wk2[k*6 + jj];
      #pragma unroll
      for (int m=0;m<MS;m++) acc[m] = fmaf(av[m], w, acc[m]);
    }
    #pragma unroll
    for (int m=0;m<MS;m++) sK6[jj*MS + m] = fminf(fmaxf(acc[m], 0.f), 1.f);
  }
  __syncthreads();

  // ---- write deta_cp and deta_knots_6 ----
  float* out_dcp = dout + (long)B*3;
  float* out_dk  = dout + (long)B*23;
  for (int idx = tid; idx < MS*20; idx += BLOCK){
    int s = idx / 20, c = idx % 20;
    if (base + s < B) out_dcp[(base+s)*20 + c] = sCPF[c*MS + s];
  }
  for (int idx = tid; idx < MS*6; idx += BLOCK){
    int s = idx / 6, c = idx % 6;
    if (base + s < B) out_dk[(base+s)*6 + c] = sK6[c*MS + s];
  }
}

// ---------------------------------------------------------------------------
// Kernel B: per-sample serial float64 geometry, fully register-resident.
// ---------------------------------------------------------------------------
extern "C" __global__ __launch_bounds__(64, 1)
void kbs_geom(const float* __restrict__ knots_g, const float* __restrict__ cp_g,
              float* __restrict__ dout, int B)
{
  const int s = blockIdx.x * 64 + threadIdx.x;
  if (s >= B) return;

  const float* dcp = dout + (long)B*3  + (long)s*20;  // deta_cp (from kernel A)
  const float* dk6 = dout + (long)B*23 + (long)s*6;   // deta_knots_6

  double u[14];
  #pragma unroll
  for (int i=0;i<14;i++){
    double d = (i>=4 && i<10) ? (double)dk6[i-4] : 0.0;
    u[i] = (double)knots_g[(long)s*14 + i] + d;
  }
  double cx[10], cy[10];
  #pragma unroll
  for (int i=0;i<10;i++){
    cx[i] = (double)cp_g[(long)s*20 + 2*i    ] + (double)dcp[2*i    ];
    cy[i] = (double)cp_g[(long)s*20 + 2*i + 1] + (double)dcp[2*i + 1];
  }

  double ang[33];
  double ppx = 0.0, ppy = 0.0;
  const double uend = u[13] - 1e-6;
  #pragma unroll
  for (int q = 0; q < 34; ++q){
    double uq = (double)q * (1.0/33.0);
    if (uq > uend) uq = uend;
    double Nb[13];
    #pragma unroll
    for (int i=0;i<13;i++)
      Nb[i] = (uq >= u[i] && uq < u[i+1]) ? 1.0 : 0.0;
    #pragma unroll
    for (int p=1;p<=3;p++){
      #pragma unroll
      for (int i=0;i+p<13;i++){
        double ld = u[i+p]   - u[i];
        double rd = u[i+p+1] - u[i+1];
        double lf = (ld > 0.0) ? (uq - u[i])     / ld : 0.0;
        double rf = (rd > 0.0) ? (u[i+p+1] - uq) / rd : 0.0;
        Nb[i] = lf*Nb[i] + rf*Nb[i+1];
      }
    }
    double px = 0.0, py = 0.0;
    #pragma unroll
    for (int i=0;i<10;i++){ px += Nb[i]*cx[i]; py += Nb[i]*cy[i]; }
    if (q > 0)
      ang[q-1] = 57.29577951308232087679815 * atan2(px - ppx, py - ppy);
    ppx = px; ppy = py;
  }

  // running first-occurrence argmax / argmin (no dynamic indexing)
  double vmax = ang[0], vmin = ang[0];
  int imax = 0, imin = 0;
  #pragma unroll
  for (int i=1;i<33;i++){
    if (ang[i] > vmax){ vmax = ang[i]; imax = i; }
    if (ang[i] < vmin){ vmin = ang[i]; imin = i; }
  }
  double mt = vmax - vmin;
  int lo = imax < imin ? imax : imin;
  int hi = imax > imin ? imax : imin;

  // predicated unrolled range reductions (static indices only)
  double uM = -1e300, um = 1e300, dM = -1e300, dm = 1e300;
  #pragma unroll
  for (int i=0;i<33;i++){
    if (i <= lo){ uM = fmax(uM, ang[i]); um = fmin(um, ang[i]); }
    if (i >= hi){ dM = fmax(dM, ang[i]); dm = fmin(dm, ang[i]); }
  }

  dout[(long)s*3 + 0] = (float)(uM - um);  // pt
  dout[(long)s*3 + 1] = (float)mt;         // mt
  dout[(long)s*3 + 2] = (float)(dM - dm);  // tl
}

extern "C" void kernel_launch(void* const* d_in, const int* in_sizes, int n_in,
                              void* d_out, int out_size, void* d_ws, size_t ws_size,
                              hipStream_t stream)
{
  const float* kp    = (const float*)d_in[0];
  const float* knots = (const float*)d_in[1];
  const float* cp    = (const float*)d_in[2];
  const float* w1  = (const float*)d_in[3];  const float* b1  = (const float*)d_in[4];
  const float* w2  = (const float*)d_in[5];  const float* b2  = (const float*)d_in[6];
  const float* w3  = (const float*)d_in[7];  const float* b3  = (const float*)d_in[8];
  const float* wc1 = (const float*)d_in[9];  const float* bc1 = (const float*)d_in[10];
  const float* wc2 = (const float*)d_in[11]; const float* bc2 = (const float*)d_in[12];
  const float* wk1 = (const float*)d_in[13]; const float* bk1 = (const float*)d_in[14];
  const float* wk2 = (const float*)d_in[15]; const float* bk2 = (const float*)d_in[16];

  const int B = in_sizes[0] / 68;           // keypoints (B,34,2)
  const int nblkA = (B + MS - 1) / MS;
  const int nblkB = (B + 63) / 64;

  hipLaunchKernelGGL(kbs_mlp, dim3(nblkA), dim3(BLOCK), 0, stream,
                     kp, w1, b1, w2, b2, w3, b3,
                     wc1, bc1, wc2, bc2, wk1, bk1, wk2, bk2,
                     (float*)d_out, B);
  hipLaunchKernelGGL(kbs_geom, dim3(nblkB), dim3(64), 0, stream,
                     knots, cp, (float*)d_out, B);
}

// Round 14
// 519.759 us; speedup vs baseline: 1.0194x; 1.0018x over previous
//
#include <hip/hip_runtime.h>
#include <math.h>

#define BLOCK 256
#define MS 16   // samples per block

// ---------------------------------------------------------------------------
// Kernel A (MLP): one block = 16 samples; thread -> (j=tid&127 col group,
// h=tid>>7 sample half); CPT cols x 8 samples per thread. Weight loads are
// software-pipelined: double-buffered register groups (wA/wB, static indexing)
// loaded one full PF-group ahead of use, so each load has >=128 cyc of FMA
// cover from its own wave. Activations ping-pong in LDS [N][16] read as
// wave-uniform float4 broadcasts. 48 KB LDS -> 3 blocks/CU.
// Kernel B (geometry): 1 thread/sample f64, hand-inlined atan2 (no libcall).
// ---------------------------------------------------------------------------

template<int CPT, int PF>
__device__ __forceinline__ void loadW(float w[PF][CPT], const float* __restrict__ p, int ld){
  #pragma unroll
  for (int q=0;q<PF;q++){
    if constexpr (CPT==4){
      float4 v = *(const float4*)(p + (size_t)q*ld);
      w[q][0]=v.x; w[q][1]=v.y; w[q][2]=v.z; w[q][3]=v.w;
    } else {
      float2 v = *(const float2*)(p + (size_t)q*ld);
      w[q][0]=v.x; w[q][1]=v.y;
    }
  }
}

template<int CPT, int PF>
__device__ __forceinline__ void fmaG(float acc[CPT][8], const float w[PF][CPT],
                                     const float* sArow, int k0){
  #pragma unroll
  for (int q=0;q<PF;q++){
    float4 a0 = *(const float4*)(sArow + (k0+q)*MS);
    float4 a1 = *(const float4*)(sArow + (k0+q)*MS + 4);
    float av[8] = {a0.x,a0.y,a0.z,a0.w,a1.x,a1.y,a1.z,a1.w};
    #pragma unroll
    for (int c=0;c<CPT;c++)
      #pragma unroll
      for (int m=0;m<8;m++) acc[c][m] = fmaf(av[m], w[q][c], acc[c][m]);
  }
}

template<int K, int CPT, int PF, bool RELU>
__device__ __forceinline__ void dense_cols(const float* __restrict__ Wcol, int ld,
                                           const float* __restrict__ Bcol,
                                           const float* sArow,   // &sA[h*8]
                                           float* sCcol)         // &sC[c0*16 + h*8]
{
  static_assert(K % PF == 0, "K divisible by PF");
  constexpr int NG = K / PF;
  float acc[CPT][8];
  #pragma unroll
  for (int c=0;c<CPT;c++){
    float b = Bcol[c];
    #pragma unroll
    for (int m=0;m<8;m++) acc[c][m] = b;
  }
  float wA[PF][CPT], wB[PF][CPT];
  const float* wp = Wcol;
  loadW<CPT,PF>(wA, wp, ld); wp += (size_t)PF*ld;
  int k0 = 0;
  #pragma unroll 1
  for (int g = 0; g + 2 <= NG; g += 2){
    loadW<CPT,PF>(wB, wp, ld); wp += (size_t)PF*ld;   // prefetch group g+1
    fmaG<CPT,PF>(acc, wA, sArow, k0); k0 += PF;       // compute group g
    if (g + 2 < NG){ loadW<CPT,PF>(wA, wp, ld); wp += (size_t)PF*ld; }  // prefetch g+2
    fmaG<CPT,PF>(acc, wB, sArow, k0); k0 += PF;       // compute group g+1
  }
  if constexpr (NG & 1){
    fmaG<CPT,PF>(acc, wA, sArow, k0);                 // tail group (prefetched)
  }
  #pragma unroll
  for (int c=0;c<CPT;c++)
    #pragma unroll
    for (int m=0;m<8;m++){
      float v = acc[c][m];
      if (RELU) v = fmaxf(v, 0.f);
      sCcol[c*MS + m] = v;
    }
}

extern "C" __global__ __launch_bounds__(BLOCK, 3)
void kbs_mlp(const float* __restrict__ kp,
             const float* __restrict__ w1, const float* __restrict__ b1,
             const float* __restrict__ w2, const float* __restrict__ b2,
             const float* __restrict__ w3, const float* __restrict__ b3,
             const float* __restrict__ wc1, const float* __restrict__ bc1,
             const float* __restrict__ wc2, const float* __restrict__ bc2,
             const float* __restrict__ wk1, const float* __restrict__ bk1,
             const float* __restrict__ wk2, const float* __restrict__ bk2,
             float* __restrict__ dout, int B)
{
  __shared__ float sA[512*MS];   // 32 KB
  __shared__ float sB[256*MS];   // 16 KB

  const int tid = threadIdx.x;
  const int j   = tid & 127;     // column-group index
  const int h   = tid >> 7;      // sample half (0/1)
  const long base = (long)blockIdx.x * MS;

  // ---- stage X = keypoints.reshape(B,68) into sA as [68][MS] ----
  for (int idx = tid; idx < 68*MS; idx += BLOCK){
    int m = idx / 68, k = idx % 68;
    float v = 0.f;
    if (base + m < B) v = kp[(base + m)*68 + k];
    sA[k*MS + m] = v;
  }
  __syncthreads();

  // ---- L1: 68 -> 256 ----
  dense_cols<68, 2, 4, true>(w1 + 2*j, 256, b1 + 2*j, sA + h*8, sB + (2*j)*MS + h*8);
  __syncthreads();
  // ---- L2: 256 -> 512 ----
  dense_cols<256, 4, 4, true>(w2 + 4*j, 512, b2 + 4*j, sB + h*8, sA + (4*j)*MS + h*8);
  __syncthreads();
  // ---- L3: 512 -> 256 (feat -> sB) ----
  dense_cols<512, 2, 8, true>(w3 + 2*j, 256, b3 + 2*j, sA + h*8, sB + (2*j)*MS + h*8);
  __syncthreads();
  // ---- heads stage 1: feat(256) -> [HC(128) | HK(128)] concat in sA ----
  {
    const int c0 = 2*j;                       // concat col (wave-uniform split)
    const float* Wp = (c0 < 128) ? (wc1 + c0) : (wk1 + (c0 - 128));
    const float* Bp = (c0 < 128) ? (bc1 + c0) : (bk1 + (c0 - 128));
    dense_cols<256, 2, 8, true>(Wp, 128, Bp, sB + h*8, sA + c0*MS + h*8);
  }
  __syncthreads();

  // ---- heads stage 2 (128->20 and 128->6) ----
  float* sCPF = sB;            // [20][MS]  (deta_cp, raw)
  float* sK6  = sB + 20*MS;    // [6][MS]   (deta_knots_6, clipped)
  if (tid < 20){
    float acc[MS];
    float b = bc2[tid];
    #pragma unroll
    for (int m=0;m<MS;m++) acc[m] = b;
    for (int k=0;k<128;k++){
      const float4* r4 = (const float4*)(sA + k*MS);   // HC row k
      float4 q0=r4[0], q1=r4[1], q2=r4[2], q3=r4[3];
      float av[MS] = {q0.x,q0.y,q0.z,q0.w,q1.x,q1.y,q1.z,q1.w,
                      q2.x,q2.y,q2.z,q2.w,q3.x,q3.y,q3.z,q3.w};
      float w = wc2[k*20 + tid];
      #pragma unroll
      for (int m=0;m<MS;m++) acc[m] = fmaf(av[m], w, acc[m]);
    }
    #pragma unroll
    for (int m=0;m<MS;m++) sCPF[tid*MS + m] = acc[m];
  } else if (tid >= 64 && tid < 70){
    const int jj = tid - 64;
    float acc[MS];
    float b = bk2[jj];
    #pragma unroll
    for (int m=0;m<MS;m++) acc[m] = b;
    for (int k=0;k<128;k++){
      const float4* r4 = (const float4*)(sA + (128+k)*MS);  // HK row k
      float4 q0=r4[0], q1=r4[1], q2=r4[2], q3=r4[3];
      float av[MS] = {q0.x,q0.y,q0.z,q0.w,q1.x,q1.y,q1.z,q1.w,
                      q2.x,q2.y,q2.z,q2.w,q3.x,q3.y,q3.z,q3.w};
      float w = wk2[k*6 + jj];
      #pragma unroll
      for (int m=0;m<MS;m++) acc[m] = fmaf(av[m], w, acc[m]);
    }
    #pragma unroll
    for (int m=0;m<MS;m++) sK6[jj*MS + m] = fminf(fmaxf(acc[m], 0.f), 1.f);
  }
  __syncthreads();

  // ---- write deta_cp and deta_knots_6 ----
  float* out_dcp = dout + (long)B*3;
  float* out_dk  = dout + (long)B*23;
  for (int idx = tid; idx < MS*20; idx += BLOCK){
    int s = idx / 20, c = idx % 20;
    if (base + s < B) out_dcp[(base+s)*20 + c] = sCPF[c*MS + s];
  }
  for (int idx = tid; idx < MS*6; idx += BLOCK){
    int s = idx / 6, c = idx % 6;
    if (base + s < B) out_dk[(base+s)*6 + c] = sK6[c*MS + s];
  }
}

// ---------------------------------------------------------------------------
// Inline f64 atan2: two-step reduction + 17-term Horner, |rel err| ~1e-14.
// ---------------------------------------------------------------------------
__device__ __forceinline__ double atan_poly(double r){
  double s = r*r;
  double p =  1.0/33.0;
  p = fma(p, s, -1.0/31.0);
  p = fma(p, s,  1.0/29.0);
  p = fma(p, s, -1.0/27.0);
  p = fma(p, s,  1.0/25.0);
  p = fma(p, s, -1.0/23.0);
  p = fma(p, s,  1.0/21.0);
  p = fma(p, s, -1.0/19.0);
  p = fma(p, s,  1.0/17.0);
  p = fma(p, s, -1.0/15.0);
  p = fma(p, s,  1.0/13.0);
  p = fma(p, s, -1.0/11.0);
  p = fma(p, s,  1.0/9.0);
  p = fma(p, s, -1.0/7.0);
  p = fma(p, s,  1.0/5.0);
  p = fma(p, s, -1.0/3.0);
  p = fma(p, s,  1.0);
  return r * p;
}

__device__ __forceinline__ double atan2_f64(double y, double x){
  double ay = fabs(y), ax = fabs(x);
  double mx = fmax(ax, ay), mn = fmin(ax, ay);
  double r  = (mx > 0.0) ? (mn / mx) : 0.0;
  const double T = 0.4142135623730950488;            // tan(pi/8)
  bool red = r > T;
  double rr = red ? ((r - 1.0) / (r + 1.0)) : r;
  double t = atan_poly(rr);
  if (red)      t += 0.78539816339744830962;         // pi/4
  if (ay > ax)  t  = 1.57079632679489661923 - t;     // pi/2 - t
  if (x < 0.0)  t  = 3.14159265358979323846 - t;     // pi  - t
  return copysign(t, y);
}

// ---------------------------------------------------------------------------
// Kernel B: per-sample serial float64 geometry, register-resident.
// ---------------------------------------------------------------------------
extern "C" __global__ __launch_bounds__(64, 1)
void kbs_geom(const float* __restrict__ knots_g, const float* __restrict__ cp_g,
              float* __restrict__ dout, int B)
{
  const int s = blockIdx.x * 64 + threadIdx.x;
  if (s >= B) return;

  const float* dcp = dout + (long)B*3  + (long)s*20;  // deta_cp (from kernel A)
  const float* dk6 = dout + (long)B*23 + (long)s*6;   // deta_knots_6

  double u[14];
  #pragma unroll
  for (int i=0;i<14;i++){
    double d = (i>=4 && i<10) ? (double)dk6[i-4] : 0.0;
    u[i] = (double)knots_g[(long)s*14 + i] + d;
  }
  double cx[10], cy[10];
  #pragma unroll
  for (int i=0;i<10;i++){
    cx[i] = (double)cp_g[(long)s*20 + 2*i    ] + (double)dcp[2*i    ];
    cy[i] = (double)cp_g[(long)s*20 + 2*i + 1] + (double)dcp[2*i + 1];
  }

  double ang[33];
  double ppx = 0.0, ppy = 0.0;
  const double uend = u[13] - 1e-6;
  #pragma unroll
  for (int q = 0; q < 34; ++q){
    double uq = (double)q * (1.0/33.0);
    if (uq > uend) uq = uend;
    double Nb[13];
    #pragma unroll
    for (int i=0;i<13;i++)
      Nb[i] = (uq >= u[i] && uq < u[i+1]) ? 1.0 : 0.0;
    #pragma unroll
    for (int p=1;p<=3;p++){
      #pragma unroll
      for (int i=0;i+p<13;i++){
        double ld = u[i+p]   - u[i];
        double rd = u[i+p+1] - u[i+1];
        double lf = (ld > 0.0) ? (uq - u[i])     / ld : 0.0;
        double rf = (rd > 0.0) ? (u[i+p+1] - uq) / rd : 0.0;
        Nb[i] = lf*Nb[i] + rf*Nb[i+1];
      }
    }
    double px = 0.0, py = 0.0;
    #pragma unroll
    for (int i=0;i<10;i++){ px += Nb[i]*cx[i]; py += Nb[i]*cy[i]; }
    if (q > 0)
      ang[q-1] = 57.29577951308232087679815 * atan2_f64(px - ppx, py - ppy);
    ppx = px; ppy = py;
  }

  // running first-occurrence argmax / argmin (no dynamic indexing)
  double vmax = ang[0], vmin = ang[0];
  int imax = 0, imin = 0;
  #pragma unroll
  for (int i=1;i<33;i++){
    if (ang[i] > vmax){ vmax = ang[i]; imax = i; }
    if (ang[i] < vmin){ vmin = ang[i]; imin = i; }
  }
  double mt = vmax - vmin;
  int lo = imax < imin ? imax : imin;
  int hi = imax > imin ? imax : imin;

  // predicated unrolled range reductions (static indices only)
  double uM = -1e300, um = 1e300, dM = -1e300, dm = 1e300;
  #pragma unroll
  for (int i=0;i<33;i++){
    if (i <= lo){ uM = fmax(uM, ang[i]); um = fmin(um, ang[i]); }
    if (i >= hi){ dM = fmax(dM, ang[i]); dm = fmin(dm, ang[i]); }
  }

  dout[(long)s*3 + 0] = (float)(uM - um);  // pt
  dout[(long)s*3 + 1] = (float)mt;         // mt
  dout[(long)s*3 + 2] = (float)(dM - dm);  // tl
}

extern "C" void kernel_launch(void* const* d_in, const int* in_sizes, int n_in,
                              void* d_out, int out_size, void* d_ws, size_t ws_size,
                              hipStream_t stream)
{
  const float* kp    = (const float*)d_in[0];
  const float* knots = (const float*)d_in[1];
  const float* cp    = (const float*)d_in[2];
  const float* w1  = (const float*)d_in[3];  const float* b1  = (const float*)d_in[4];
  const float* w2  = (const float*)d_in[5];  const float* b2  = (const float*)d_in[6];
  const float* w3  = (const float*)d_in[7];  const float* b3  = (const float*)d_in[8];
  const float* wc1 = (const float*)d_in[9];  const float* bc1 = (const float*)d_in[10];
  const float* wc2 = (const float*)d_in[11]; const float* bc2 = (const float*)d_in[12];
  const float* wk1 = (const float*)d_in[13]; const float* bk1 = (const float*)d_in[14];
  const float* wk2 = (const float*)d_in[15]; const float* bk2 = (const float*)d_in[16];

  const int B = in_sizes[0] / 68;           // keypoints (B,34,2)
  const int nblkA = (B + MS - 1) / MS;
  const int nblkB = (B + 63) / 64;

  hipLaunchKernelGGL(kbs_mlp, dim3(nblkA), dim3(BLOCK), 0, stream,
                     kp, w1, b1, w2, b2, w3, b3,
                     wc1, bc1, wc2, bc2, wk1, bk1, wk2, bk2,
                     (float*)d_out, B);
  hipLaunchKernelGGL(kbs_geom, dim3(nblkB), dim3(64), 0, stream,
                     knots, cp, (float*)d_out, B);
}